// Round 7
// baseline (292.688 us; speedup 1.0000x reference)
//
#include <hip/hip_runtime.h>
#include <hip/hip_bf16.h>

typedef __attribute__((ext_vector_type(8))) short short8;
typedef __attribute__((ext_vector_type(4))) short s16x4;
typedef __attribute__((ext_vector_type(4))) float f32x4;

typedef const __attribute__((address_space(1))) unsigned* gp1;
typedef __attribute__((address_space(3))) unsigned* lp3;

__device__ inline short f2bf(float f) {
    union { float f; unsigned u; } v; v.f = f;
    unsigned r = v.u + 0x7fffu + ((v.u >> 16) & 1u);
    return (short)(r >> 16);
}

// ---------------------------------------------------------------------------
// P0: fp32 -> bf16 flat convert (x)
// ---------------------------------------------------------------------------
__global__ __launch_bounds__(256) void cvt_bf16(
    const float* __restrict__ src, short* __restrict__ dst, int n4)
{
    int i = blockIdx.x * 256 + threadIdx.x;
    if (i < n4) {
        float4 v = ((const float4*)src)[i];
        s16x4 o = { f2bf(v.x), f2bf(v.y), f2bf(v.z), f2bf(v.w) };
        ((s16x4*)dst)[i] = o;
    }
}

// ---------------------------------------------------------------------------
// P1: W[K][N] fp32 -> W^T[N][K] bf16 (64x64 LDS tile transpose)
// ---------------------------------------------------------------------------
__global__ __launch_bounds__(256) void tr_w(
    const float* __restrict__ src, short* __restrict__ dst, int K, int N)
{
    __shared__ float t[64][65];
    const int k0 = blockIdx.x * 64, n0 = blockIdx.y * 64;
    const int r = threadIdx.x >> 4, c4 = (threadIdx.x & 15) * 4;
#pragma unroll
    for (int j = 0; j < 4; j++) {
        float4 v = *(const float4*)(src + (size_t)(k0 + r + 16 * j) * N + n0 + c4);
        t[r + 16 * j][c4 + 0] = v.x; t[r + 16 * j][c4 + 1] = v.y;
        t[r + 16 * j][c4 + 2] = v.z; t[r + 16 * j][c4 + 3] = v.w;
    }
    __syncthreads();
#pragma unroll
    for (int j = 0; j < 4; j++) {
        const int n = r + 16 * j;
        s16x4 o = { f2bf(t[c4 + 0][n]), f2bf(t[c4 + 1][n]),
                    f2bf(t[c4 + 2][n]), f2bf(t[c4 + 3][n]) };
        *(s16x4*)(dst + (size_t)(n0 + n) * K + k0 + c4) = o;
    }
}

// ---------------------------------------------------------------------------
// K1: qkv = xb @ WqT^T  (M=8192, K=512, N=1536), m97-style 128x128 tile.
//     (R6's coalesced-v + tr_v was measured NEUTRAL -> reverted to scatter.)
// ---------------------------------------------------------------------------
__global__ __launch_bounds__(256) void qkv_gemm(
    const short* __restrict__ A, const short* __restrict__ BT,
    short* __restrict__ q, short* __restrict__ k, short* __restrict__ vt)
{
    __shared__ short sA[128][32];   // NO padding: global_load_lds needs dense
    __shared__ short sB[128][32];

    const int tid  = threadIdx.x;
    const int wv   = tid >> 6, lane = tid & 63;
    const int quad = lane >> 4, l16 = lane & 15;
    const int wr = wv >> 1, wc = wv & 1;
    const int m0 = blockIdx.x * 128, n0 = blockIdx.y * 128;

    f32x4 acc[4][4];
#pragma unroll
    for (int i = 0; i < 4; i++)
#pragma unroll
        for (int j = 0; j < 4; j++) acc[i][j] = (f32x4){0.f, 0.f, 0.f, 0.f};

    const short* a_src = A  + (size_t)(m0 + wv * 32 + (lane >> 2)) * 512 + (lane & 3) * 8;
    const short* b_src = BT + (size_t)(n0 + wv * 32 + (lane >> 2)) * 512 + (lane & 3) * 8;
    char* a_dst = (char*)sA + wv * 2048;
    char* b_dst = (char*)sB + wv * 2048;

    for (int ks = 0; ks < 16; ks++) {
        __syncthreads();
        const short* ap = a_src + ks * 32;
        const short* bp = b_src + ks * 32;
        __builtin_amdgcn_global_load_lds((gp1)(ap),            (lp3)(a_dst),        16, 0, 0);
        __builtin_amdgcn_global_load_lds((gp1)(ap + 16 * 512), (lp3)(a_dst + 1024), 16, 0, 0);
        __builtin_amdgcn_global_load_lds((gp1)(bp),            (lp3)(b_dst),        16, 0, 0);
        __builtin_amdgcn_global_load_lds((gp1)(bp + 16 * 512), (lp3)(b_dst + 1024), 16, 0, 0);
        __syncthreads();

        short8 af[4], bf[4];
#pragma unroll
        for (int f = 0; f < 4; f++) {
            af[f] = *(const short8*)&sA[wr * 64 + f * 16 + l16][quad * 8];
            bf[f] = *(const short8*)&sB[wc * 64 + f * 16 + l16][quad * 8];
        }
#pragma unroll
        for (int fm = 0; fm < 4; fm++)
#pragma unroll
            for (int fn = 0; fn < 4; fn++)
                acc[fm][fn] = __builtin_amdgcn_mfma_f32_16x16x32_bf16(
                    af[fm], bf[fn], acc[fm][fn], 0, 0, 0);
    }

    const int sec = n0 >> 9;   // 0=q 1=k 2=v
#pragma unroll
    for (int fn = 0; fn < 4; fn++) {
        const int gc = n0 + wc * 64 + fn * 16 + l16;
        const int cc = gc & 511;
        const int h = cc >> 6, d = cc & 63;
#pragma unroll
        for (int fm = 0; fm < 4; fm++)
#pragma unroll
            for (int i = 0; i < 4; i++) {
                const int gm = m0 + wr * 64 + fm * 16 + quad * 4 + i;
                const int b = gm >> 10, n = gm & 1023;
                const int bh = b * 8 + h;
                if (sec == 0)      q[((size_t)(bh * 1024 + n)) * 64 + d] = f2bf(acc[fm][fn][i] * 0.125f);
                else if (sec == 1) k[((size_t)(bh * 1024 + n)) * 64 + d] = f2bf(acc[fm][fn][i]);
                else               vt[((size_t)(bh * 64 + d)) * 1024 + n] = f2bf(acc[fm][fn][i]);
            }
    }
}

// ---------------------------------------------------------------------------
// K2: attention (R7).
//   R6 lesson: attn invariant at ~121us with every visible pipe idle >=73%;
//   estimated LDS-pipe busy 50-65% + 48 barriers/block coupling 4 waves.
//   Sweep1 needs NO cross-wave K sharing once K is L2-hot (128KB/bh, 16
//   consecutive blocks share it) -> R7 sweep1 reads K fragments DIRECTLY
//   from global, reg-batched 8 loads -> 8 MFMAs, ZERO barriers, ZERO LDS.
//   Sweep2 (K+V LDS-shared, online softmax with fo/fov domain fix) = R5
//   verbatim. LDS 37.4 -> 27.9 KB. Tripwire: WRITE_SIZE must stay ~8.2MB.
// ---------------------------------------------------------------------------
__global__ __launch_bounds__(256, 4) void attn_k(
    const short* __restrict__ q, const short* __restrict__ kk,
    const short* __restrict__ vt, const float* __restrict__ spd,
    const float* __restrict__ hm, short* __restrict__ o)
{
    __shared__ short sK[64][72];
    __shared__ short sV[64][72];
    __shared__ short sP[4][16][72];
    __shared__ float sred[4][16];

    const int tid  = threadIdx.x;
    const int wv   = tid >> 6, lane = tid & 63;
    const int quad = lane >> 4, l16 = lane & 15;
    const int qt = blockIdx.x, bh = blockIdx.y;
    const int b = bh >> 3, h = bh & 7;
    const int q0 = qt * 64;

    // Q as B-operand: lane l16 = q-col, quad*8 = d
    const short* qb = q + ((size_t)bh * 1024 + q0 + wv * 16 + l16) * 64;
    short8 aq0 = *(const short8*)(qb + quad * 8);
    short8 aq1 = *(const short8*)(qb + 32 + quad * 8);

    // staging map for sweep2: thread -> row sr (and sr+32), 16B col chunk sc
    const int sr = tid & 31, sc = (tid >> 5) * 8;
    const short* ksrc = kk + (size_t)bh * 65536 + (size_t)sr * 64 + sc;    // keys as rows
    const short* vsrc = vt + (size_t)bh * 65536 + (size_t)sr * 1024 + sc;  // d as rows
    const float* sp   = spd + ((size_t)b * 1024 + q0 + wv * 16 + l16) * 1024 + quad * 4;

    // ======== sweep 1: row norms. K DIRECT from global (L2-hot). ==========
    // No barriers, no LDS: waves free-run and hide each other's latency.
    // Fragment addr: row = key (t*16 + l16), col = quad*8 (+32) — the exact
    // layout sweep2 reads from sK, just sourced from global.
    const short* kfrag = kk + (size_t)bh * 65536 + (size_t)l16 * 64 + quad * 8;
    float dn = 0.f, pn = 0.f;
    for (int c = 0; c < 16; ++c) {
        short8 kf0[4], kf1[4];
#pragma unroll
        for (int t = 0; t < 4; t++) {
            const short* kp = kfrag + (size_t)(c * 64 + t * 16) * 64;
            kf0[t] = *(const short8*)(kp);
            kf1[t] = *(const short8*)(kp + 32);
        }
        float4 sv0 = *(const float4*)(sp + c * 64 +  0);
        float4 sv1 = *(const float4*)(sp + c * 64 + 16);
        float4 sv2 = *(const float4*)(sp + c * 64 + 32);
        float4 sv3 = *(const float4*)(sp + c * 64 + 48);
        f32x4 a[4];
#pragma unroll
        for (int t = 0; t < 4; t++) {
            a[t] = (f32x4){0.f, 0.f, 0.f, 0.f};
            a[t] = __builtin_amdgcn_mfma_f32_16x16x32_bf16(kf0[t], aq0, a[t], 0, 0, 0);
            a[t] = __builtin_amdgcn_mfma_f32_16x16x32_bf16(kf1[t], aq1, a[t], 0, 0, 0);
        }
        const float4 svv[4] = {sv0, sv1, sv2, sv3};
#pragma unroll
        for (int t = 0; t < 4; t++)
#pragma unroll
            for (int i = 0; i < 4; i++) {
                float s  = a[t][i];
                float sv = ((const float*)&svv[t])[i];
                float ps = s * sv;
                dn = fmaf(s, s, dn);
                pn = fmaf(ps, ps, pn);
            }
    }
    dn += __shfl_xor(dn, 16, 64); dn += __shfl_xor(dn, 32, 64);
    pn += __shfl_xor(pn, 16, 64); pn += __shfl_xor(pn, 32, 64);
    const float ratio = sqrtf(dn) / fmaxf(sqrtf(pn), 1e-12f);   // per q-row l16

    // ======== sweep 2: bias + online softmax + PV (R5 verbatim) ===========
    float m_r = -1e30f, ls = 0.f;
    f32x4 O[4];
#pragma unroll
    for (int dt = 0; dt < 4; dt++) O[dt] = (f32x4){0.f, 0.f, 0.f, 0.f};

    short8 k0 = *(const short8*)(ksrc);
    short8 k1 = *(const short8*)(ksrc + 2048);
    short8 v0 = *(const short8*)(vsrc);
    short8 v1 = *(const short8*)(vsrc + 32768);

    for (int c = 0; c < 16; ++c) {
        __syncthreads();
        *(short8*)&sK[sr][sc]      = k0;
        *(short8*)&sK[sr + 32][sc] = k1;
        *(short8*)&sV[sr][sc]      = v0;
        *(short8*)&sV[sr + 32][sc] = v1;
        __syncthreads();
        // spd for this chunk (issued now, consumed after QK mfmas)
        float4 svc0 = *(const float4*)(sp + c * 64 +  0);
        float4 svc1 = *(const float4*)(sp + c * 64 + 16);
        float4 svc2 = *(const float4*)(sp + c * 64 + 32);
        float4 svc3 = *(const float4*)(sp + c * 64 + 48);
        if (c < 15) {
            k0 = *(const short8*)(ksrc + (c + 1) * 4096);
            k1 = *(const short8*)(ksrc + (c + 1) * 4096 + 2048);
            v0 = *(const short8*)(vsrc + (c + 1) * 64);
            v1 = *(const short8*)(vsrc + (c + 1) * 64 + 32768);
        }
        f32x4 a[4];
#pragma unroll
        for (int t = 0; t < 4; t++) {
            a[t] = (f32x4){0.f, 0.f, 0.f, 0.f};
            a[t] = __builtin_amdgcn_mfma_f32_16x16x32_bf16(
                *(const short8*)&sK[t * 16 + l16][quad * 8], aq0, a[t], 0, 0, 0);
            a[t] = __builtin_amdgcn_mfma_f32_16x16x32_bf16(
                *(const short8*)&sK[t * 16 + l16][32 + quad * 8], aq1, a[t], 0, 0, 0);
        }
        // bias + chunk max (per q-row l16)
        const float4 svv[4] = {svc0, svc1, svc2, svc3};
        float mx = -1e30f;
#pragma unroll
        for (int t = 0; t < 4; t++)
#pragma unroll
            for (int i = 0; i < 4; i++) {
                float s  = a[t][i];
                float sv = ((const float*)&svv[t])[i];
                float l  = s * fmaf(sv, ratio, 1.0f);
                a[t][i] = l;
                mx = fmaxf(mx, l);
            }
        mx = fmaxf(mx, __shfl_xor(mx, 16, 64));
        mx = fmaxf(mx, __shfl_xor(mx, 32, 64));        // row-uniform chunk max
        const float m_new = fmaxf(m_r, mx);
        const float fo = __expf(m_r - m_new);          // rescale for row l16
        m_r = m_new;
        ls *= fo;
        // O rows are q=quad*4+i (D-layout); fo's row domain is l16 (R5 fix)
        float fov[4];
#pragma unroll
        for (int i = 0; i < 4; i++) fov[i] = __shfl(fo, quad * 4 + i, 16);
#pragma unroll
        for (int dt = 0; dt < 4; dt++) {
            O[dt][0] *= fov[0]; O[dt][1] *= fov[1];
            O[dt][2] *= fov[2]; O[dt][3] *= fov[3];
        }
        // exp + pack P (row l16 domain)
#pragma unroll
        for (int t = 0; t < 4; t++) {
            float p0 = __expf(a[t][0] - m_r);
            float p1 = __expf(a[t][1] - m_r);
            float p2 = __expf(a[t][2] - m_r);
            float p3 = __expf(a[t][3] - m_r);
            ls += (p0 + p1) + (p2 + p3);
            s16x4 pk = { f2bf(p0), f2bf(p1), f2bf(p2), f2bf(p3) };
            *(s16x4*)&sP[wv][l16][t * 16 + quad * 4] = pk;
        }
        // PV (same-wave sP round trip)
#pragma unroll
        for (int kc = 0; kc < 2; kc++) {
            short8 pa = *(const short8*)&sP[wv][l16][kc * 32 + quad * 8];
#pragma unroll
            for (int dt = 0; dt < 4; dt++) {
                short8 vf = *(const short8*)&sV[dt * 16 + l16][kc * 32 + quad * 8];
                O[dt] = __builtin_amdgcn_mfma_f32_16x16x32_bf16(pa, vf, O[dt], 0, 0, 0);
            }
        }
    }
    // final normalization; ls is lane-partial -> row total (row l16)
    ls += __shfl_xor(ls, 16, 64); ls += __shfl_xor(ls, 32, 64);
    const float hsum = hm[0] + hm[1] + hm[2] + hm[3] + hm[4] + hm[5] + hm[6] + hm[7];
    const float rinv = hm[h] * 8.0f / (hsum * ls);     // per l16-row
    if (quad == 0) sred[wv][l16] = rinv;
    __syncthreads();
    float rv[4];
#pragma unroll
    for (int i = 0; i < 4; i++) rv[i] = sred[wv][quad * 4 + i];
#pragma unroll
    for (int dt = 0; dt < 4; dt++)
#pragma unroll
        for (int i = 0; i < 4; i++)
            o[((size_t)(b * 1024 + q0 + wv * 16 + quad * 4 + i)) * 512 + h * 64 + dt * 16 + l16]
                = f2bf(O[dt][i] * rv[i]);
}

// ---------------------------------------------------------------------------
// K3: out = O @ WoT^T + b_out  (M=8192, K=512, N=512), 128x128 tile, fp32 out
// ---------------------------------------------------------------------------
__global__ __launch_bounds__(256) void out_gemm(
    const short* __restrict__ A, const short* __restrict__ BT,
    const float* __restrict__ bias, float* __restrict__ out)
{
    __shared__ short sA[128][32];
    __shared__ short sB[128][32];

    const int tid  = threadIdx.x;
    const int wv   = tid >> 6, lane = tid & 63;
    const int quad = lane >> 4, l16 = lane & 15;
    const int wr = wv >> 1, wc = wv & 1;
    const int m0 = blockIdx.x * 128, n0 = blockIdx.y * 128;

    f32x4 acc[4][4];
#pragma unroll
    for (int i = 0; i < 4; i++)
#pragma unroll
        for (int j = 0; j < 4; j++) acc[i][j] = (f32x4){0.f, 0.f, 0.f, 0.f};

    const short* a_src = A  + (size_t)(m0 + wv * 32 + (lane >> 2)) * 512 + (lane & 3) * 8;
    const short* b_src = BT + (size_t)(n0 + wv * 32 + (lane >> 2)) * 512 + (lane & 3) * 8;
    char* a_dst = (char*)sA + wv * 2048;
    char* b_dst = (char*)sB + wv * 2048;

    for (int ks = 0; ks < 16; ks++) {
        __syncthreads();
        const short* ap = a_src + ks * 32;
        const short* bp = b_src + ks * 32;
        __builtin_amdgcn_global_load_lds((gp1)(ap),            (lp3)(a_dst),        16, 0, 0);
        __builtin_amdgcn_global_load_lds((gp1)(ap + 16 * 512), (lp3)(a_dst + 1024), 16, 0, 0);
        __builtin_amdgcn_global_load_lds((gp1)(bp),            (lp3)(b_dst),        16, 0, 0);
        __builtin_amdgcn_global_load_lds((gp1)(bp + 16 * 512), (lp3)(b_dst + 1024), 16, 0, 0);
        __syncthreads();

        short8 af[4], bf[4];
#pragma unroll
        for (int f = 0; f < 4; f++) {
            af[f] = *(const short8*)&sA[wr * 64 + f * 16 + l16][quad * 8];
            bf[f] = *(const short8*)&sB[wc * 64 + f * 16 + l16][quad * 8];
        }
#pragma unroll
        for (int fm = 0; fm < 4; fm++)
#pragma unroll
            for (int fn = 0; fn < 4; fn++)
                acc[fm][fn] = __builtin_amdgcn_mfma_f32_16x16x32_bf16(
                    af[fm], bf[fn], acc[fm][fn], 0, 0, 0);
    }

#pragma unroll
    for (int fn = 0; fn < 4; fn++) {
        const int gc = n0 + wc * 64 + fn * 16 + l16;
        const float bv = bias[gc];
#pragma unroll
        for (int fm = 0; fm < 4; fm++)
#pragma unroll
            for (int i = 0; i < 4; i++) {
                const int gm = m0 + wr * 64 + fm * 16 + quad * 4 + i;
                out[(size_t)gm * 512 + gc] = acc[fm][fn][i] + bv;
            }
    }
}

// ---------------------------------------------------------------------------
extern "C" void kernel_launch(void* const* d_in, const int* in_sizes, int n_in,
                              void* d_out, int out_size, void* d_ws, size_t ws_size,
                              hipStream_t stream) {
    const float* x    = (const float*)d_in[0];
    const float* spd  = (const float*)d_in[1];
    const float* hm   = (const float*)d_in[2];
    const float* Wqkv = (const float*)d_in[3];
    const float* Wout = (const float*)d_in[4];
    const float* bout = (const float*)d_in[5];
    float* out = (float*)d_out;

    char* ws = (char*)d_ws;
    short* qw  = (short*)(ws);                      // 8 MB  [bh][n][d] bf16 (pre-scaled)
    short* kw  = (short*)(ws + ((size_t)8  << 20)); // 8 MB  [bh][n][d] bf16
    short* vtw = (short*)(ws + ((size_t)16 << 20)); // 8 MB  [bh][d][n] bf16
    short* ow  = (short*)(ws + ((size_t)24 << 20)); // 8 MB  [b][n][h*64+d] bf16
    short* xb  = (short*)(ws + ((size_t)32 << 20)); // 8 MB  x bf16 [8192][512]
    short* wqT = (short*)(ws + ((size_t)40 << 20)); // 1.5MB Wqkv^T bf16 [1536][512]
    short* woT = (short*)(ws + ((size_t)42 << 20)); // 0.5MB Wout^T bf16 [512][512]

    cvt_bf16<<<4096, 256, 0, stream>>>(x, xb, 8192 * 512 / 4);
    tr_w    <<<dim3(8, 24), 256, 0, stream>>>(Wqkv, wqT, 512, 1536);
    tr_w    <<<dim3(8, 8),  256, 0, stream>>>(Wout, woT, 512, 512);

    qkv_gemm<<<dim3(64, 12), 256, 0, stream>>>(xb, wqT, qw, kw, vtw);
    attn_k  <<<dim3(16, 64), 256, 0, stream>>>(qw, kw, vtw, spd, hm, ow);
    out_gemm<<<dim3(64, 4),  256, 0, stream>>>(ow, woT, bout, out);
}

// Round 8
// 247.765 us; speedup vs baseline: 1.1813x; 1.1813x over previous
//
#include <hip/hip_runtime.h>
#include <hip/hip_bf16.h>

typedef __attribute__((ext_vector_type(8))) short short8;
typedef __attribute__((ext_vector_type(4))) short s16x4;
typedef __attribute__((ext_vector_type(4))) float f32x4;

typedef const __attribute__((address_space(1))) unsigned* gp1;
typedef __attribute__((address_space(3))) unsigned* lp3;

__device__ inline short f2bf(float f) {
    union { float f; unsigned u; } v; v.f = f;
    unsigned r = v.u + 0x7fffu + ((v.u >> 16) & 1u);
    return (short)(r >> 16);
}

// ---------------------------------------------------------------------------
// P0: fp32 -> bf16 flat convert (x)
// ---------------------------------------------------------------------------
__global__ __launch_bounds__(256) void cvt_bf16(
    const float* __restrict__ src, short* __restrict__ dst, int n4)
{
    int i = blockIdx.x * 256 + threadIdx.x;
    if (i < n4) {
        float4 v = ((const float4*)src)[i];
        s16x4 o = { f2bf(v.x), f2bf(v.y), f2bf(v.z), f2bf(v.w) };
        ((s16x4*)dst)[i] = o;
    }
}

// ---------------------------------------------------------------------------
// P1: W[K][N] fp32 -> W^T[N][K] bf16 (64x64 LDS tile transpose)
// ---------------------------------------------------------------------------
__global__ __launch_bounds__(256) void tr_w(
    const float* __restrict__ src, short* __restrict__ dst, int K, int N)
{
    __shared__ float t[64][65];
    const int k0 = blockIdx.x * 64, n0 = blockIdx.y * 64;
    const int r = threadIdx.x >> 4, c4 = (threadIdx.x & 15) * 4;
#pragma unroll
    for (int j = 0; j < 4; j++) {
        float4 v = *(const float4*)(src + (size_t)(k0 + r + 16 * j) * N + n0 + c4);
        t[r + 16 * j][c4 + 0] = v.x; t[r + 16 * j][c4 + 1] = v.y;
        t[r + 16 * j][c4 + 2] = v.z; t[r + 16 * j][c4 + 3] = v.w;
    }
    __syncthreads();
#pragma unroll
    for (int j = 0; j < 4; j++) {
        const int n = r + 16 * j;
        s16x4 o = { f2bf(t[c4 + 0][n]), f2bf(t[c4 + 1][n]),
                    f2bf(t[c4 + 2][n]), f2bf(t[c4 + 3][n]) };
        *(s16x4*)(dst + (size_t)(n0 + n) * K + k0 + c4) = o;
    }
}

// ---------------------------------------------------------------------------
// K1: qkv = xb @ WqT^T  (M=8192, K=512, N=1536), m97-style 128x128 tile.
// ---------------------------------------------------------------------------
__global__ __launch_bounds__(256) void qkv_gemm(
    const short* __restrict__ A, const short* __restrict__ BT,
    short* __restrict__ q, short* __restrict__ k, short* __restrict__ vt)
{
    __shared__ short sA[128][32];   // NO padding: global_load_lds needs dense
    __shared__ short sB[128][32];

    const int tid  = threadIdx.x;
    const int wv   = tid >> 6, lane = tid & 63;
    const int quad = lane >> 4, l16 = lane & 15;
    const int wr = wv >> 1, wc = wv & 1;
    const int m0 = blockIdx.x * 128, n0 = blockIdx.y * 128;

    f32x4 acc[4][4];
#pragma unroll
    for (int i = 0; i < 4; i++)
#pragma unroll
        for (int j = 0; j < 4; j++) acc[i][j] = (f32x4){0.f, 0.f, 0.f, 0.f};

    const short* a_src = A  + (size_t)(m0 + wv * 32 + (lane >> 2)) * 512 + (lane & 3) * 8;
    const short* b_src = BT + (size_t)(n0 + wv * 32 + (lane >> 2)) * 512 + (lane & 3) * 8;
    char* a_dst = (char*)sA + wv * 2048;
    char* b_dst = (char*)sB + wv * 2048;

    for (int ks = 0; ks < 16; ks++) {
        __syncthreads();
        const short* ap = a_src + ks * 32;
        const short* bp = b_src + ks * 32;
        __builtin_amdgcn_global_load_lds((gp1)(ap),            (lp3)(a_dst),        16, 0, 0);
        __builtin_amdgcn_global_load_lds((gp1)(ap + 16 * 512), (lp3)(a_dst + 1024), 16, 0, 0);
        __builtin_amdgcn_global_load_lds((gp1)(bp),            (lp3)(b_dst),        16, 0, 0);
        __builtin_amdgcn_global_load_lds((gp1)(bp + 16 * 512), (lp3)(b_dst + 1024), 16, 0, 0);
        __syncthreads();

        short8 af[4], bf[4];
#pragma unroll
        for (int f = 0; f < 4; f++) {
            af[f] = *(const short8*)&sA[wr * 64 + f * 16 + l16][quad * 8];
            bf[f] = *(const short8*)&sB[wc * 64 + f * 16 + l16][quad * 8];
        }
#pragma unroll
        for (int fm = 0; fm < 4; fm++)
#pragma unroll
            for (int fn = 0; fn < 4; fn++)
                acc[fm][fn] = __builtin_amdgcn_mfma_f32_16x16x32_bf16(
                    af[fm], bf[fn], acc[fm][fn], 0, 0, 0);
    }

    const int sec = n0 >> 9;   // 0=q 1=k 2=v
#pragma unroll
    for (int fn = 0; fn < 4; fn++) {
        const int gc = n0 + wc * 64 + fn * 16 + l16;
        const int cc = gc & 511;
        const int h = cc >> 6, d = cc & 63;
#pragma unroll
        for (int fm = 0; fm < 4; fm++)
#pragma unroll
            for (int i = 0; i < 4; i++) {
                const int gm = m0 + wr * 64 + fm * 16 + quad * 4 + i;
                const int b = gm >> 10, n = gm & 1023;
                const int bh = b * 8 + h;
                if (sec == 0)      q[((size_t)(bh * 1024 + n)) * 64 + d] = f2bf(acc[fm][fn][i] * 0.125f);
                else if (sec == 1) k[((size_t)(bh * 1024 + n)) * 64 + d] = f2bf(acc[fm][fn][i]);
                else               vt[((size_t)(bh * 64 + d)) * 1024 + n] = f2bf(acc[fm][fn][i]);
            }
    }
}

// ---------------------------------------------------------------------------
// K2: attention (R8): two-pass with PRECOMPUTED MAX BOUND -> sweep2 has NO
//     cross-lane ops in the chunk loop.
//   R7 lesson: sweep1 must stay LDS-staged (direct-global = 4x L2 requests,
//   163us). R6 lesson: barriers/spd-bytes aren't the bottleneck. The 121us
//   invariant = sweep2's serial chain, 6 shuffles/chunk (max reduce + fov).
//   R8: sweep1 also tracks mxs=max(s), mxp=max(s*spd). Then
//     Mhat = mxs + ratio*mxp >= max_k l   (max(a+b)<=max a+max b, ratio>=0)
//   and sweep2 uses fixed Mhat: p=exp(l-Mhat) — uniformly scaled by e^-d,
//   renormalized by rinv => numerically exact in relative terms (d~8-15,
//   p>=1e-7 >> bf16 min normal). No running max, no fo/fov shuffles, no
//   O-rescale. ls stays lane-local, reduced once at the end.
//   LDS 27.9KB -> 5 blocks/CU. Tripwire: WRITE_SIZE must stay ~8.2MB.
// ---------------------------------------------------------------------------
__global__ __launch_bounds__(256, 4) void attn_k(
    const short* __restrict__ q, const short* __restrict__ kk,
    const short* __restrict__ vt, const float* __restrict__ spd,
    const float* __restrict__ hm, short* __restrict__ o)
{
    __shared__ short sK[64][72];
    __shared__ short sV[64][72];
    __shared__ short sP[4][16][72];
    __shared__ float sred[4][16];

    const int tid  = threadIdx.x;
    const int wv   = tid >> 6, lane = tid & 63;
    const int quad = lane >> 4, l16 = lane & 15;
    const int qt = blockIdx.x, bh = blockIdx.y;
    const int b = bh >> 3, h = bh & 7;
    const int q0 = qt * 64;

    // Q as B-operand: lane l16 = q-col, quad*8 = d
    const short* qb = q + ((size_t)bh * 1024 + q0 + wv * 16 + l16) * 64;
    short8 aq0 = *(const short8*)(qb + quad * 8);
    short8 aq1 = *(const short8*)(qb + 32 + quad * 8);

    // staging map: thread -> row sr (and sr+32), 16B col chunk sc
    const int sr = tid & 31, sc = (tid >> 5) * 8;
    const short* ksrc = kk + (size_t)bh * 65536 + (size_t)sr * 64 + sc;    // keys as rows
    const short* vsrc = vt + (size_t)bh * 65536 + (size_t)sr * 1024 + sc;  // d as rows
    const float* sp   = spd + ((size_t)b * 1024 + q0 + wv * 16 + l16) * 1024 + quad * 4;

    // ===== sweep 1: row norms + max bound (LDS-staged K, R5 form) =========
    float dn = 0.f, pn = 0.f, mxs = -1e30f, mxp = -1e30f;
    short8 k0 = *(const short8*)(ksrc);
    short8 k1 = *(const short8*)(ksrc + 2048);
    float4 sv0 = *(const float4*)(sp +  0);
    float4 sv1 = *(const float4*)(sp + 16);
    float4 sv2 = *(const float4*)(sp + 32);
    float4 sv3 = *(const float4*)(sp + 48);

    for (int c = 0; c < 16; ++c) {
        __syncthreads();
        *(short8*)&sK[sr][sc]      = k0;
        *(short8*)&sK[sr + 32][sc] = k1;
        __syncthreads();
        float4 svc0 = sv0, svc1 = sv1, svc2 = sv2, svc3 = sv3;
        if (c < 15) {
            k0 = *(const short8*)(ksrc + (c + 1) * 4096);
            k1 = *(const short8*)(ksrc + (c + 1) * 4096 + 2048);
            sv0 = *(const float4*)(sp + (c + 1) * 64 +  0);
            sv1 = *(const float4*)(sp + (c + 1) * 64 + 16);
            sv2 = *(const float4*)(sp + (c + 1) * 64 + 32);
            sv3 = *(const float4*)(sp + (c + 1) * 64 + 48);
        }
        f32x4 a[4];
#pragma unroll
        for (int t = 0; t < 4; t++) {
            a[t] = (f32x4){0.f, 0.f, 0.f, 0.f};
            a[t] = __builtin_amdgcn_mfma_f32_16x16x32_bf16(
                *(const short8*)&sK[t * 16 + l16][quad * 8], aq0, a[t], 0, 0, 0);
            a[t] = __builtin_amdgcn_mfma_f32_16x16x32_bf16(
                *(const short8*)&sK[t * 16 + l16][32 + quad * 8], aq1, a[t], 0, 0, 0);
        }
        const float4 svv[4] = {svc0, svc1, svc2, svc3};
#pragma unroll
        for (int t = 0; t < 4; t++)
#pragma unroll
            for (int i = 0; i < 4; i++) {
                float s  = a[t][i];
                float sv = ((const float*)&svv[t])[i];
                float ps = s * sv;
                dn = fmaf(s, s, dn);
                pn = fmaf(ps, ps, pn);
                mxs = fmaxf(mxs, s);
                mxp = fmaxf(mxp, ps);
            }
    }
    dn  += __shfl_xor(dn, 16, 64);  dn  += __shfl_xor(dn, 32, 64);
    pn  += __shfl_xor(pn, 16, 64);  pn  += __shfl_xor(pn, 32, 64);
    mxs = fmaxf(mxs, __shfl_xor(mxs, 16, 64)); mxs = fmaxf(mxs, __shfl_xor(mxs, 32, 64));
    mxp = fmaxf(mxp, __shfl_xor(mxp, 16, 64)); mxp = fmaxf(mxp, __shfl_xor(mxp, 32, 64));
    const float ratio = sqrtf(dn) / fmaxf(sqrtf(pn), 1e-12f);   // per q-row l16
    const float Mhat  = mxs + ratio * mxp;                      // >= max_k l, per row l16

    // ===== sweep 2: bias + FIXED-MAX softmax + PV (no cross-lane ops) =====
    float ls = 0.f;
    f32x4 O[4];
#pragma unroll
    for (int dt = 0; dt < 4; dt++) O[dt] = (f32x4){0.f, 0.f, 0.f, 0.f};

    k0 = *(const short8*)(ksrc);
    k1 = *(const short8*)(ksrc + 2048);
    short8 v0 = *(const short8*)(vsrc);
    short8 v1 = *(const short8*)(vsrc + 32768);

    for (int c = 0; c < 16; ++c) {
        __syncthreads();
        *(short8*)&sK[sr][sc]      = k0;
        *(short8*)&sK[sr + 32][sc] = k1;
        *(short8*)&sV[sr][sc]      = v0;
        *(short8*)&sV[sr + 32][sc] = v1;
        __syncthreads();
        float4 svc0 = *(const float4*)(sp + c * 64 +  0);
        float4 svc1 = *(const float4*)(sp + c * 64 + 16);
        float4 svc2 = *(const float4*)(sp + c * 64 + 32);
        float4 svc3 = *(const float4*)(sp + c * 64 + 48);
        if (c < 15) {
            k0 = *(const short8*)(ksrc + (c + 1) * 4096);
            k1 = *(const short8*)(ksrc + (c + 1) * 4096 + 2048);
            v0 = *(const short8*)(vsrc + (c + 1) * 64);
            v1 = *(const short8*)(vsrc + (c + 1) * 64 + 32768);
        }
        f32x4 a[4];
#pragma unroll
        for (int t = 0; t < 4; t++) {
            a[t] = (f32x4){0.f, 0.f, 0.f, 0.f};
            a[t] = __builtin_amdgcn_mfma_f32_16x16x32_bf16(
                *(const short8*)&sK[t * 16 + l16][quad * 8], aq0, a[t], 0, 0, 0);
            a[t] = __builtin_amdgcn_mfma_f32_16x16x32_bf16(
                *(const short8*)&sK[t * 16 + l16][32 + quad * 8], aq1, a[t], 0, 0, 0);
        }
        // bias + exp(l - Mhat) + pack; all lane-local (row l16 domain)
        const float4 svv[4] = {svc0, svc1, svc2, svc3};
#pragma unroll
        for (int t = 0; t < 4; t++) {
            float p0, p1, p2, p3;
            {
                float s = a[t][0], sv = ((const float*)&svv[t])[0];
                p0 = __expf(s * fmaf(sv, ratio, 1.0f) - Mhat);
            }
            {
                float s = a[t][1], sv = ((const float*)&svv[t])[1];
                p1 = __expf(s * fmaf(sv, ratio, 1.0f) - Mhat);
            }
            {
                float s = a[t][2], sv = ((const float*)&svv[t])[2];
                p2 = __expf(s * fmaf(sv, ratio, 1.0f) - Mhat);
            }
            {
                float s = a[t][3], sv = ((const float*)&svv[t])[3];
                p3 = __expf(s * fmaf(sv, ratio, 1.0f) - Mhat);
            }
            ls += (p0 + p1) + (p2 + p3);
            s16x4 pk = { f2bf(p0), f2bf(p1), f2bf(p2), f2bf(p3) };
            *(s16x4*)&sP[wv][l16][t * 16 + quad * 4] = pk;
        }
        // PV (same-wave sP round trip)
#pragma unroll
        for (int kc = 0; kc < 2; kc++) {
            short8 pa = *(const short8*)&sP[wv][l16][kc * 32 + quad * 8];
#pragma unroll
            for (int dt = 0; dt < 4; dt++) {
                short8 vf = *(const short8*)&sV[dt * 16 + l16][kc * 32 + quad * 8];
                O[dt] = __builtin_amdgcn_mfma_f32_16x16x32_bf16(pa, vf, O[dt], 0, 0, 0);
            }
        }
    }
    // final normalization; ls is lane-partial -> row total (row l16)
    ls += __shfl_xor(ls, 16, 64); ls += __shfl_xor(ls, 32, 64);
    const float hsum = hm[0] + hm[1] + hm[2] + hm[3] + hm[4] + hm[5] + hm[6] + hm[7];
    const float rinv = hm[h] * 8.0f / (hsum * ls);     // per l16-row
    if (quad == 0) sred[wv][l16] = rinv;
    __syncthreads();
    float rv[4];
#pragma unroll
    for (int i = 0; i < 4; i++) rv[i] = sred[wv][quad * 4 + i];
#pragma unroll
    for (int dt = 0; dt < 4; dt++)
#pragma unroll
        for (int i = 0; i < 4; i++)
            o[((size_t)(b * 1024 + q0 + wv * 16 + quad * 4 + i)) * 512 + h * 64 + dt * 16 + l16]
                = f2bf(O[dt][i] * rv[i]);
}

// ---------------------------------------------------------------------------
// K3: out = O @ WoT^T + b_out  (M=8192, K=512, N=512), 128x128 tile, fp32 out
// ---------------------------------------------------------------------------
__global__ __launch_bounds__(256) void out_gemm(
    const short* __restrict__ A, const short* __restrict__ BT,
    const float* __restrict__ bias, float* __restrict__ out)
{
    __shared__ short sA[128][32];
    __shared__ short sB[128][32];

    const int tid  = threadIdx.x;
    const int wv   = tid >> 6, lane = tid & 63;
    const int quad = lane >> 4, l16 = lane & 15;
    const int wr = wv >> 1, wc = wv & 1;
    const int m0 = blockIdx.x * 128, n0 = blockIdx.y * 128;

    f32x4 acc[4][4];
#pragma unroll
    for (int i = 0; i < 4; i++)
#pragma unroll
        for (int j = 0; j < 4; j++) acc[i][j] = (f32x4){0.f, 0.f, 0.f, 0.f};

    const short* a_src = A  + (size_t)(m0 + wv * 32 + (lane >> 2)) * 512 + (lane & 3) * 8;
    const short* b_src = BT + (size_t)(n0 + wv * 32 + (lane >> 2)) * 512 + (lane & 3) * 8;
    char* a_dst = (char*)sA + wv * 2048;
    char* b_dst = (char*)sB + wv * 2048;

    for (int ks = 0; ks < 16; ks++) {
        __syncthreads();
        const short* ap = a_src + ks * 32;
        const short* bp = b_src + ks * 32;
        __builtin_amdgcn_global_load_lds((gp1)(ap),            (lp3)(a_dst),        16, 0, 0);
        __builtin_amdgcn_global_load_lds((gp1)(ap + 16 * 512), (lp3)(a_dst + 1024), 16, 0, 0);
        __builtin_amdgcn_global_load_lds((gp1)(bp),            (lp3)(b_dst),        16, 0, 0);
        __builtin_amdgcn_global_load_lds((gp1)(bp + 16 * 512), (lp3)(b_dst + 1024), 16, 0, 0);
        __syncthreads();

        short8 af[4], bf[4];
#pragma unroll
        for (int f = 0; f < 4; f++) {
            af[f] = *(const short8*)&sA[wr * 64 + f * 16 + l16][quad * 8];
            bf[f] = *(const short8*)&sB[wc * 64 + f * 16 + l16][quad * 8];
        }
#pragma unroll
        for (int fm = 0; fm < 4; fm++)
#pragma unroll
            for (int fn = 0; fn < 4; fn++)
                acc[fm][fn] = __builtin_amdgcn_mfma_f32_16x16x32_bf16(
                    af[fm], bf[fn], acc[fm][fn], 0, 0, 0);
    }

#pragma unroll
    for (int fn = 0; fn < 4; fn++) {
        const int gc = n0 + wc * 64 + fn * 16 + l16;
        const float bv = bias[gc];
#pragma unroll
        for (int fm = 0; fm < 4; fm++)
#pragma unroll
            for (int i = 0; i < 4; i++) {
                const int gm = m0 + wr * 64 + fm * 16 + quad * 4 + i;
                out[(size_t)gm * 512 + gc] = acc[fm][fn][i] + bv;
            }
    }
}

// ---------------------------------------------------------------------------
extern "C" void kernel_launch(void* const* d_in, const int* in_sizes, int n_in,
                              void* d_out, int out_size, void* d_ws, size_t ws_size,
                              hipStream_t stream) {
    const float* x    = (const float*)d_in[0];
    const float* spd  = (const float*)d_in[1];
    const float* hm   = (const float*)d_in[2];
    const float* Wqkv = (const float*)d_in[3];
    const float* Wout = (const float*)d_in[4];
    const float* bout = (const float*)d_in[5];
    float* out = (float*)d_out;

    char* ws = (char*)d_ws;
    short* qw  = (short*)(ws);                      // 8 MB  [bh][n][d] bf16 (pre-scaled)
    short* kw  = (short*)(ws + ((size_t)8  << 20)); // 8 MB  [bh][n][d] bf16
    short* vtw = (short*)(ws + ((size_t)16 << 20)); // 8 MB  [bh][d][n] bf16
    short* ow  = (short*)(ws + ((size_t)24 << 20)); // 8 MB  [b][n][h*64+d] bf16
    short* xb  = (short*)(ws + ((size_t)32 << 20)); // 8 MB  x bf16 [8192][512]
    short* wqT = (short*)(ws + ((size_t)40 << 20)); // 1.5MB Wqkv^T bf16 [1536][512]
    short* woT = (short*)(ws + ((size_t)42 << 20)); // 0.5MB Wout^T bf16 [512][512]

    cvt_bf16<<<4096, 256, 0, stream>>>(x, xb, 8192 * 512 / 4);
    tr_w    <<<dim3(8, 24), 256, 0, stream>>>(Wqkv, wqT, 512, 1536);
    tr_w    <<<dim3(8, 8),  256, 0, stream>>>(Wout, woT, 512, 512);

    qkv_gemm<<<dim3(64, 12), 256, 0, stream>>>(xb, wqT, qw, kw, vtw);
    attn_k  <<<dim3(16, 64), 256, 0, stream>>>(qw, kw, vtw, spd, hm, ow);
    out_gemm<<<dim3(64, 4),  256, 0, stream>>>(ow, woT, bout, out);
}

// Round 9
// 242.706 us; speedup vs baseline: 1.2059x; 1.0208x over previous
//
#include <hip/hip_runtime.h>
#include <hip/hip_bf16.h>

typedef __attribute__((ext_vector_type(8))) short short8;
typedef __attribute__((ext_vector_type(4))) short s16x4;
typedef __attribute__((ext_vector_type(4))) float f32x4;

typedef const __attribute__((address_space(1))) unsigned* gp1;
typedef __attribute__((address_space(3))) unsigned* lp3;

__device__ inline short f2bf(float f) {
    union { float f; unsigned u; } v; v.f = f;
    unsigned r = v.u + 0x7fffu + ((v.u >> 16) & 1u);
    return (short)(r >> 16);
}

// ---------------------------------------------------------------------------
// P0: fp32 -> bf16 flat convert (x)
// ---------------------------------------------------------------------------
__global__ __launch_bounds__(256) void cvt_bf16(
    const float* __restrict__ src, short* __restrict__ dst, int n4)
{
    int i = blockIdx.x * 256 + threadIdx.x;
    if (i < n4) {
        float4 v = ((const float4*)src)[i];
        s16x4 o = { f2bf(v.x), f2bf(v.y), f2bf(v.z), f2bf(v.w) };
        ((s16x4*)dst)[i] = o;
    }
}

// ---------------------------------------------------------------------------
// P1: W[K][N] fp32 -> W^T[N][K] bf16 (64x64 LDS tile transpose)
// ---------------------------------------------------------------------------
__global__ __launch_bounds__(256) void tr_w(
    const float* __restrict__ src, short* __restrict__ dst, int K, int N)
{
    __shared__ float t[64][65];
    const int k0 = blockIdx.x * 64, n0 = blockIdx.y * 64;
    const int r = threadIdx.x >> 4, c4 = (threadIdx.x & 15) * 4;
#pragma unroll
    for (int j = 0; j < 4; j++) {
        float4 v = *(const float4*)(src + (size_t)(k0 + r + 16 * j) * N + n0 + c4);
        t[r + 16 * j][c4 + 0] = v.x; t[r + 16 * j][c4 + 1] = v.y;
        t[r + 16 * j][c4 + 2] = v.z; t[r + 16 * j][c4 + 3] = v.w;
    }
    __syncthreads();
#pragma unroll
    for (int j = 0; j < 4; j++) {
        const int n = r + 16 * j;
        s16x4 o = { f2bf(t[c4 + 0][n]), f2bf(t[c4 + 1][n]),
                    f2bf(t[c4 + 2][n]), f2bf(t[c4 + 3][n]) };
        *(s16x4*)(dst + (size_t)(n0 + n) * K + k0 + c4) = o;
    }
}

// ---------------------------------------------------------------------------
// K1: qkv = xb @ WqT^T  (M=8192, K=512, N=1536).
//     R9: 128x64 tiles (was 128x128). Theory: grid 768->1536 blocks raises
//     blocks/CU 3 -> 4-6 (VGPR ~80 caps 4 waves/SIMD); the 2-barrier K-step
//     drain overlaps across more resident blocks. Same staging pattern,
//     rows stay 64B (no new bank conflicts). acc[2][4], 8 MFMA/step.
// ---------------------------------------------------------------------------
__global__ __launch_bounds__(256) void qkv_gemm(
    const short* __restrict__ A, const short* __restrict__ BT,
    short* __restrict__ q, short* __restrict__ k, short* __restrict__ vt)
{
    __shared__ short sA[128][32];   // NO padding: global_load_lds needs dense
    __shared__ short sB[64][32];

    const int tid  = threadIdx.x;
    const int wv   = tid >> 6, lane = tid & 63;
    const int quad = lane >> 4, l16 = lane & 15;
    const int m0 = blockIdx.x * 128, n0 = blockIdx.y * 64;

    f32x4 acc[2][4];
#pragma unroll
    for (int i = 0; i < 2; i++)
#pragma unroll
        for (int j = 0; j < 4; j++) acc[i][j] = (f32x4){0.f, 0.f, 0.f, 0.f};

    // staging: A rows wv*32 + j*16 + (lane>>2); B rows wv*16 + (lane>>2)
    const short* a_src = A  + (size_t)(m0 + wv * 32 + (lane >> 2)) * 512 + (lane & 3) * 8;
    const short* b_src = BT + (size_t)(n0 + wv * 16 + (lane >> 2)) * 512 + (lane & 3) * 8;
    char* a_dst = (char*)sA + wv * 2048;
    char* b_dst = (char*)sB + wv * 1024;

    for (int ks = 0; ks < 16; ks++) {
        __syncthreads();
        const short* ap = a_src + ks * 32;
        const short* bp = b_src + ks * 32;
        __builtin_amdgcn_global_load_lds((gp1)(ap),            (lp3)(a_dst),        16, 0, 0);
        __builtin_amdgcn_global_load_lds((gp1)(ap + 16 * 512), (lp3)(a_dst + 1024), 16, 0, 0);
        __builtin_amdgcn_global_load_lds((gp1)(bp),            (lp3)(b_dst),        16, 0, 0);
        __syncthreads();

        short8 af[2], bf[4];
#pragma unroll
        for (int f = 0; f < 2; f++)
            af[f] = *(const short8*)&sA[wv * 32 + f * 16 + l16][quad * 8];
#pragma unroll
        for (int f = 0; f < 4; f++)
            bf[f] = *(const short8*)&sB[f * 16 + l16][quad * 8];
#pragma unroll
        for (int fm = 0; fm < 2; fm++)
#pragma unroll
            for (int fn = 0; fn < 4; fn++)
                acc[fm][fn] = __builtin_amdgcn_mfma_f32_16x16x32_bf16(
                    af[fm], bf[fn], acc[fm][fn], 0, 0, 0);
    }

    // epilogue: section is uniform per block (n0 multiple of 64, sections 512-aligned)
    const int sec = n0 >> 9;   // 0=q 1=k 2=v
#pragma unroll
    for (int fn = 0; fn < 4; fn++) {
        const int gc = n0 + fn * 16 + l16;
        const int cc = gc & 511;
        const int h = cc >> 6, d = cc & 63;
#pragma unroll
        for (int fm = 0; fm < 2; fm++)
#pragma unroll
            for (int i = 0; i < 4; i++) {
                const int gm = m0 + wv * 32 + fm * 16 + quad * 4 + i;
                const int b = gm >> 10, n = gm & 1023;
                const int bh = b * 8 + h;
                if (sec == 0)      q[((size_t)(bh * 1024 + n)) * 64 + d] = f2bf(acc[fm][fn][i] * 0.125f);
                else if (sec == 1) k[((size_t)(bh * 1024 + n)) * 64 + d] = f2bf(acc[fm][fn][i]);
                else               vt[((size_t)(bh * 64 + d)) * 1024 + n] = f2bf(acc[fm][fn][i]);
            }
    }
}

// ---------------------------------------------------------------------------
// K2: attention (R8, FROZEN — control for this round): two-pass with
//     precomputed max bound; sweep2 has no cross-lane ops in the chunk loop.
//   Sweep1 LDS-staged (R7: direct-global = 4x L2 requests = +42us).
//   Mhat = mxs + ratio*mxp >= max l; p=exp(l-Mhat) uniformly scaled,
//   renormalized by rinv => exact in relative terms.
//   Tripwire: WRITE_SIZE must stay ~8.2MB.
// ---------------------------------------------------------------------------
__global__ __launch_bounds__(256, 4) void attn_k(
    const short* __restrict__ q, const short* __restrict__ kk,
    const short* __restrict__ vt, const float* __restrict__ spd,
    const float* __restrict__ hm, short* __restrict__ o)
{
    __shared__ short sK[64][72];
    __shared__ short sV[64][72];
    __shared__ short sP[4][16][72];
    __shared__ float sred[4][16];

    const int tid  = threadIdx.x;
    const int wv   = tid >> 6, lane = tid & 63;
    const int quad = lane >> 4, l16 = lane & 15;
    const int qt = blockIdx.x, bh = blockIdx.y;
    const int b = bh >> 3, h = bh & 7;
    const int q0 = qt * 64;

    // Q as B-operand: lane l16 = q-col, quad*8 = d
    const short* qb = q + ((size_t)bh * 1024 + q0 + wv * 16 + l16) * 64;
    short8 aq0 = *(const short8*)(qb + quad * 8);
    short8 aq1 = *(const short8*)(qb + 32 + quad * 8);

    // staging map: thread -> row sr (and sr+32), 16B col chunk sc
    const int sr = tid & 31, sc = (tid >> 5) * 8;
    const short* ksrc = kk + (size_t)bh * 65536 + (size_t)sr * 64 + sc;    // keys as rows
    const short* vsrc = vt + (size_t)bh * 65536 + (size_t)sr * 1024 + sc;  // d as rows
    const float* sp   = spd + ((size_t)b * 1024 + q0 + wv * 16 + l16) * 1024 + quad * 4;

    // ===== sweep 1: row norms + max bound (LDS-staged K) ==================
    float dn = 0.f, pn = 0.f, mxs = -1e30f, mxp = -1e30f;
    short8 k0 = *(const short8*)(ksrc);
    short8 k1 = *(const short8*)(ksrc + 2048);
    float4 sv0 = *(const float4*)(sp +  0);
    float4 sv1 = *(const float4*)(sp + 16);
    float4 sv2 = *(const float4*)(sp + 32);
    float4 sv3 = *(const float4*)(sp + 48);

    for (int c = 0; c < 16; ++c) {
        __syncthreads();
        *(short8*)&sK[sr][sc]      = k0;
        *(short8*)&sK[sr + 32][sc] = k1;
        __syncthreads();
        float4 svc0 = sv0, svc1 = sv1, svc2 = sv2, svc3 = sv3;
        if (c < 15) {
            k0 = *(const short8*)(ksrc + (c + 1) * 4096);
            k1 = *(const short8*)(ksrc + (c + 1) * 4096 + 2048);
            sv0 = *(const float4*)(sp + (c + 1) * 64 +  0);
            sv1 = *(const float4*)(sp + (c + 1) * 64 + 16);
            sv2 = *(const float4*)(sp + (c + 1) * 64 + 32);
            sv3 = *(const float4*)(sp + (c + 1) * 64 + 48);
        }
        f32x4 a[4];
#pragma unroll
        for (int t = 0; t < 4; t++) {
            a[t] = (f32x4){0.f, 0.f, 0.f, 0.f};
            a[t] = __builtin_amdgcn_mfma_f32_16x16x32_bf16(
                *(const short8*)&sK[t * 16 + l16][quad * 8], aq0, a[t], 0, 0, 0);
            a[t] = __builtin_amdgcn_mfma_f32_16x16x32_bf16(
                *(const short8*)&sK[t * 16 + l16][32 + quad * 8], aq1, a[t], 0, 0, 0);
        }
        const float4 svv[4] = {svc0, svc1, svc2, svc3};
#pragma unroll
        for (int t = 0; t < 4; t++)
#pragma unroll
            for (int i = 0; i < 4; i++) {
                float s  = a[t][i];
                float sv = ((const float*)&svv[t])[i];
                float ps = s * sv;
                dn = fmaf(s, s, dn);
                pn = fmaf(ps, ps, pn);
                mxs = fmaxf(mxs, s);
                mxp = fmaxf(mxp, ps);
            }
    }
    dn  += __shfl_xor(dn, 16, 64);  dn  += __shfl_xor(dn, 32, 64);
    pn  += __shfl_xor(pn, 16, 64);  pn  += __shfl_xor(pn, 32, 64);
    mxs = fmaxf(mxs, __shfl_xor(mxs, 16, 64)); mxs = fmaxf(mxs, __shfl_xor(mxs, 32, 64));
    mxp = fmaxf(mxp, __shfl_xor(mxp, 16, 64)); mxp = fmaxf(mxp, __shfl_xor(mxp, 32, 64));
    const float ratio = sqrtf(dn) / fmaxf(sqrtf(pn), 1e-12f);   // per q-row l16
    const float Mhat  = mxs + ratio * mxp;                      // >= max_k l, per row l16

    // ===== sweep 2: bias + FIXED-MAX softmax + PV (no cross-lane ops) =====
    float ls = 0.f;
    f32x4 O[4];
#pragma unroll
    for (int dt = 0; dt < 4; dt++) O[dt] = (f32x4){0.f, 0.f, 0.f, 0.f};

    k0 = *(const short8*)(ksrc);
    k1 = *(const short8*)(ksrc + 2048);
    short8 v0 = *(const short8*)(vsrc);
    short8 v1 = *(const short8*)(vsrc + 32768);

    for (int c = 0; c < 16; ++c) {
        __syncthreads();
        *(short8*)&sK[sr][sc]      = k0;
        *(short8*)&sK[sr + 32][sc] = k1;
        *(short8*)&sV[sr][sc]      = v0;
        *(short8*)&sV[sr + 32][sc] = v1;
        __syncthreads();
        float4 svc0 = *(const float4*)(sp + c * 64 +  0);
        float4 svc1 = *(const float4*)(sp + c * 64 + 16);
        float4 svc2 = *(const float4*)(sp + c * 64 + 32);
        float4 svc3 = *(const float4*)(sp + c * 64 + 48);
        if (c < 15) {
            k0 = *(const short8*)(ksrc + (c + 1) * 4096);
            k1 = *(const short8*)(ksrc + (c + 1) * 4096 + 2048);
            v0 = *(const short8*)(vsrc + (c + 1) * 64);
            v1 = *(const short8*)(vsrc + (c + 1) * 64 + 32768);
        }
        f32x4 a[4];
#pragma unroll
        for (int t = 0; t < 4; t++) {
            a[t] = (f32x4){0.f, 0.f, 0.f, 0.f};
            a[t] = __builtin_amdgcn_mfma_f32_16x16x32_bf16(
                *(const short8*)&sK[t * 16 + l16][quad * 8], aq0, a[t], 0, 0, 0);
            a[t] = __builtin_amdgcn_mfma_f32_16x16x32_bf16(
                *(const short8*)&sK[t * 16 + l16][32 + quad * 8], aq1, a[t], 0, 0, 0);
        }
        // bias + exp(l - Mhat) + pack; all lane-local (row l16 domain)
        const float4 svv[4] = {svc0, svc1, svc2, svc3};
#pragma unroll
        for (int t = 0; t < 4; t++) {
            float p0, p1, p2, p3;
            {
                float s = a[t][0], sv = ((const float*)&svv[t])[0];
                p0 = __expf(s * fmaf(sv, ratio, 1.0f) - Mhat);
            }
            {
                float s = a[t][1], sv = ((const float*)&svv[t])[1];
                p1 = __expf(s * fmaf(sv, ratio, 1.0f) - Mhat);
            }
            {
                float s = a[t][2], sv = ((const float*)&svv[t])[2];
                p2 = __expf(s * fmaf(sv, ratio, 1.0f) - Mhat);
            }
            {
                float s = a[t][3], sv = ((const float*)&svv[t])[3];
                p3 = __expf(s * fmaf(sv, ratio, 1.0f) - Mhat);
            }
            ls += (p0 + p1) + (p2 + p3);
            s16x4 pk = { f2bf(p0), f2bf(p1), f2bf(p2), f2bf(p3) };
            *(s16x4*)&sP[wv][l16][t * 16 + quad * 4] = pk;
        }
        // PV (same-wave sP round trip)
#pragma unroll
        for (int kc = 0; kc < 2; kc++) {
            short8 pa = *(const short8*)&sP[wv][l16][kc * 32 + quad * 8];
#pragma unroll
            for (int dt = 0; dt < 4; dt++) {
                short8 vf = *(const short8*)&sV[dt * 16 + l16][kc * 32 + quad * 8];
                O[dt] = __builtin_amdgcn_mfma_f32_16x16x32_bf16(pa, vf, O[dt], 0, 0, 0);
            }
        }
    }
    // final normalization; ls is lane-partial -> row total (row l16)
    ls += __shfl_xor(ls, 16, 64); ls += __shfl_xor(ls, 32, 64);
    const float hsum = hm[0] + hm[1] + hm[2] + hm[3] + hm[4] + hm[5] + hm[6] + hm[7];
    const float rinv = hm[h] * 8.0f / (hsum * ls);     // per l16-row
    if (quad == 0) sred[wv][l16] = rinv;
    __syncthreads();
    float rv[4];
#pragma unroll
    for (int i = 0; i < 4; i++) rv[i] = sred[wv][quad * 4 + i];
#pragma unroll
    for (int dt = 0; dt < 4; dt++)
#pragma unroll
        for (int i = 0; i < 4; i++)
            o[((size_t)(b * 1024 + q0 + wv * 16 + quad * 4 + i)) * 512 + h * 64 + dt * 16 + l16]
                = f2bf(O[dt][i] * rv[i]);
}

// ---------------------------------------------------------------------------
// K3: out = O @ WoT^T + b_out  (M=8192, K=512, N=512).
//     R9: 128x64 tiles -> grid (64,8) = 512 blocks = 2 blocks/CU (was 256=1).
// ---------------------------------------------------------------------------
__global__ __launch_bounds__(256) void out_gemm(
    const short* __restrict__ A, const short* __restrict__ BT,
    const float* __restrict__ bias, float* __restrict__ out)
{
    __shared__ short sA[128][32];
    __shared__ short sB[64][32];

    const int tid  = threadIdx.x;
    const int wv   = tid >> 6, lane = tid & 63;
    const int quad = lane >> 4, l16 = lane & 15;
    const int m0 = blockIdx.x * 128, n0 = blockIdx.y * 64;

    f32x4 acc[2][4];
#pragma unroll
    for (int i = 0; i < 2; i++)
#pragma unroll
        for (int j = 0; j < 4; j++) acc[i][j] = (f32x4){0.f, 0.f, 0.f, 0.f};

    const short* a_src = A  + (size_t)(m0 + wv * 32 + (lane >> 2)) * 512 + (lane & 3) * 8;
    const short* b_src = BT + (size_t)(n0 + wv * 16 + (lane >> 2)) * 512 + (lane & 3) * 8;
    char* a_dst = (char*)sA + wv * 2048;
    char* b_dst = (char*)sB + wv * 1024;

    for (int ks = 0; ks < 16; ks++) {
        __syncthreads();
        const short* ap = a_src + ks * 32;
        const short* bp = b_src + ks * 32;
        __builtin_amdgcn_global_load_lds((gp1)(ap),            (lp3)(a_dst),        16, 0, 0);
        __builtin_amdgcn_global_load_lds((gp1)(ap + 16 * 512), (lp3)(a_dst + 1024), 16, 0, 0);
        __builtin_amdgcn_global_load_lds((gp1)(bp),            (lp3)(b_dst),        16, 0, 0);
        __syncthreads();

        short8 af[2], bf[4];
#pragma unroll
        for (int f = 0; f < 2; f++)
            af[f] = *(const short8*)&sA[wv * 32 + f * 16 + l16][quad * 8];
#pragma unroll
        for (int f = 0; f < 4; f++)
            bf[f] = *(const short8*)&sB[f * 16 + l16][quad * 8];
#pragma unroll
        for (int fm = 0; fm < 2; fm++)
#pragma unroll
            for (int fn = 0; fn < 4; fn++)
                acc[fm][fn] = __builtin_amdgcn_mfma_f32_16x16x32_bf16(
                    af[fm], bf[fn], acc[fm][fn], 0, 0, 0);
    }

#pragma unroll
    for (int fn = 0; fn < 4; fn++) {
        const int gc = n0 + fn * 16 + l16;
        const float bv = bias[gc];
#pragma unroll
        for (int fm = 0; fm < 2; fm++)
#pragma unroll
            for (int i = 0; i < 4; i++) {
                const int gm = m0 + wv * 32 + fm * 16 + quad * 4 + i;
                out[(size_t)gm * 512 + gc] = acc[fm][fn][i] + bv;
            }
    }
}

// ---------------------------------------------------------------------------
extern "C" void kernel_launch(void* const* d_in, const int* in_sizes, int n_in,
                              void* d_out, int out_size, void* d_ws, size_t ws_size,
                              hipStream_t stream) {
    const float* x    = (const float*)d_in[0];
    const float* spd  = (const float*)d_in[1];
    const float* hm   = (const float*)d_in[2];
    const float* Wqkv = (const float*)d_in[3];
    const float* Wout = (const float*)d_in[4];
    const float* bout = (const float*)d_in[5];
    float* out = (float*)d_out;

    char* ws = (char*)d_ws;
    short* qw  = (short*)(ws);                      // 8 MB  [bh][n][d] bf16 (pre-scaled)
    short* kw  = (short*)(ws + ((size_t)8  << 20)); // 8 MB  [bh][n][d] bf16
    short* vtw = (short*)(ws + ((size_t)16 << 20)); // 8 MB  [bh][d][n] bf16
    short* ow  = (short*)(ws + ((size_t)24 << 20)); // 8 MB  [b][n][h*64+d] bf16
    short* xb  = (short*)(ws + ((size_t)32 << 20)); // 8 MB  x bf16 [8192][512]
    short* wqT = (short*)(ws + ((size_t)40 << 20)); // 1.5MB Wqkv^T bf16 [1536][512]
    short* woT = (short*)(ws + ((size_t)42 << 20)); // 0.5MB Wout^T bf16 [512][512]

    cvt_bf16<<<4096, 256, 0, stream>>>(x, xb, 8192 * 512 / 4);
    tr_w    <<<dim3(8, 24), 256, 0, stream>>>(Wqkv, wqT, 512, 1536);
    tr_w    <<<dim3(8, 8),  256, 0, stream>>>(Wout, woT, 512, 512);

    qkv_gemm<<<dim3(64, 24), 256, 0, stream>>>(xb, wqT, qw, kw, vtw);
    attn_k  <<<dim3(16, 64), 256, 0, stream>>>(qw, kw, vtw, spd, hm, ow);
    out_gemm<<<dim3(64, 8),  256, 0, stream>>>(ow, woT, bout, out);
}